// Round 2
// baseline (7366.473 us; speedup 1.0000x reference)
//
#include <hip/hip_runtime.h>

typedef unsigned short u16;
typedef unsigned int u32;

#define EPS 1e-5f

__device__ __forceinline__ float bf2f(u16 v){ return __uint_as_float(((u32)v)<<16); }
__device__ __forceinline__ u16 f2bf(float f){
  u32 u = __float_as_uint(f);
  u32 r = u + 0x7fffu + ((u>>16)&1u);
  return (u16)(r>>16);
}

// ---------------- input projection: h = x @ W_in + b_in ----------------
__global__ __launch_bounds__(256) void k_in(const float* __restrict__ x,
    const float* __restrict__ Win, const float* __restrict__ bin,
    float* __restrict__ h, int N){
  __shared__ float Ws[18][64];
  __shared__ float xs[64][20];
  int tid = threadIdx.x;
  for (int i = tid; i < 18*64; i += 256) Ws[i>>6][i&63] = Win[i];
  int row0 = blockIdx.x * 64;
  for (int i = tid; i < 64*18; i += 256){
    int r = i/18, k = i - r*18;
    int row = row0 + r;
    xs[r][k] = (row < N) ? x[(size_t)row*18 + k] : 0.f;
  }
  __syncthreads();
  int rq = tid >> 4, dq = tid & 15;
  float4 b4 = *(const float4*)(bin + dq*4);
  float acc[4][4];
  #pragma unroll
  for (int j=0;j<4;j++){ acc[j][0]=b4.x; acc[j][1]=b4.y; acc[j][2]=b4.z; acc[j][3]=b4.w; }
  for (int k=0;k<18;k++){
    float4 wv = *(const float4*)&Ws[k][dq*4];
    #pragma unroll
    for (int j=0;j<4;j++){
      float v = xs[rq*4+j][k];
      acc[j][0]+=v*wv.x; acc[j][1]+=v*wv.y; acc[j][2]+=v*wv.z; acc[j][3]+=v*wv.w;
    }
  }
  #pragma unroll
  for (int j=0;j<4;j++){
    int row = row0 + rq*4 + j;
    if (row < N)
      *(float4*)(h + (size_t)row*64 + dq*4) = make_float4(acc[j][0],acc[j][1],acc[j][2],acc[j][3]);
  }
}

// ---------------- P = h@A, Q = h@B (A,B are 64x64) ----------------
__global__ __launch_bounds__(256) void k_pq(const float* __restrict__ h,
    const float* __restrict__ A, const float* __restrict__ B,
    float* __restrict__ P, float* __restrict__ Q, int N){
  __shared__ float hs[64][68];
  __shared__ float As[64][64];
  __shared__ float Bs[64][64];
  int tid = threadIdx.x;
  for (int i = tid; i < 4096; i += 256){ As[i>>6][i&63] = A[i]; Bs[i>>6][i&63] = B[i]; }
  int row0 = blockIdx.x*64;
  for (int i = tid; i < 4096; i += 256){
    int r = i>>6, k = i&63; int row = row0+r;
    hs[r][k] = (row<N)? h[(size_t)row*64+k] : 0.f;
  }
  __syncthreads();
  int rq = tid>>4, dq = tid&15;
  float ap[4][4]={}, aq[4][4]={};
  for (int k=0;k<64;k+=4){
    float4 hv[4];
    #pragma unroll
    for (int j=0;j<4;j++) hv[j] = *(const float4*)&hs[rq*4+j][k];
    #pragma unroll
    for (int kk=0;kk<4;kk++){
      float4 av = *(const float4*)&As[k+kk][dq*4];
      float4 bv = *(const float4*)&Bs[k+kk][dq*4];
      #pragma unroll
      for (int j=0;j<4;j++){
        float v = ((const float*)&hv[j])[kk];
        ap[j][0]+=v*av.x; ap[j][1]+=v*av.y; ap[j][2]+=v*av.z; ap[j][3]+=v*av.w;
        aq[j][0]+=v*bv.x; aq[j][1]+=v*bv.y; aq[j][2]+=v*bv.z; aq[j][3]+=v*bv.w;
      }
    }
  }
  #pragma unroll
  for (int j=0;j<4;j++){
    int row = row0 + rq*4 + j;
    if (row<N){
      *(float4*)(P+(size_t)row*64+dq*4) = make_float4(ap[j][0],ap[j][1],ap[j][2],ap[j][3]);
      *(float4*)(Q+(size_t)row*64+dq*4) = make_float4(aq[j][0],aq[j][1],aq[j][2],aq[j][3]);
    }
  }
}

// ------- stats of t (msg layer1 pre-BN) without storing t -------
__global__ __launch_bounds__(256) void k_s1(const float* __restrict__ P, const float* __restrict__ Q,
    const float* __restrict__ ea, const int* __restrict__ ei,
    const float* __restrict__ c1, const float* __restrict__ b1,
    float* __restrict__ stats, int E){
  int tid = threadIdx.x;
  int d = tid & 63, w = tid >> 6;
  float cv = c1[d], bv = b1[d];
  float s = 0.f, sq = 0.f;
  for (int e = blockIdx.x*4 + w; e < E; e += gridDim.x*4){
    int dn = ei[E+e], sn = ei[e];
    float t = P[(size_t)dn*64+d] + Q[(size_t)sn*64+d] + ea[e]*cv + bv;
    s += t; sq += t*t;
  }
  __shared__ float sS[4][64], qS[4][64];
  sS[w][d] = s; qS[w][d] = sq;
  __syncthreads();
  if (tid < 64){
    float ts = sS[0][tid]+sS[1][tid]+sS[2][tid]+sS[3][tid];
    float tq = qS[0][tid]+qS[1][tid]+qS[2][tid]+qS[3][tid];
    atomicAdd(&stats[tid], ts);
    atomicAdd(&stats[64+tid], tq);
  }
}

// ---- msg layer2: recompute t, bn1+relu, @W2+b2 -> (t2 bf16 if STORE) + stats2 ----
template<int STORE>
__global__ __launch_bounds__(256) void k_m2(const float* __restrict__ P, const float* __restrict__ Q,
    const float* __restrict__ ea, const int* __restrict__ ei,
    const float* __restrict__ c1, const float* __restrict__ b1,
    const float* __restrict__ g1, const float* __restrict__ be1,
    const float* __restrict__ stats1,
    const float* __restrict__ W2, const float* __restrict__ b2,
    u16* __restrict__ t2, float* __restrict__ stats2, int E, float invE){
  __shared__ float ys[64][68];
  __shared__ float Ws[64][64];
  __shared__ float scS[64], c1S[64], bS[64], b2S[64];
  int tid = threadIdx.x;
  if (tid < 64){
    float m = stats1[tid]*invE;
    float v = stats1[64+tid]*invE - m*m;
    float sc = g1[tid]*rsqrtf(v + EPS);
    float sh = be1[tid] - m*sc;
    scS[tid] = sc;
    c1S[tid] = c1[tid]*sc;
    bS[tid]  = b1[tid]*sc + sh;
    b2S[tid] = b2[tid];
  }
  for (int i=tid;i<4096;i+=256) Ws[i>>6][i&63] = W2[i];
  __syncthreads();
  int rq = tid>>4, dq = tid&15;
  float ssum[4]={}, ssq[4]={};
  int ntiles = (E+63)>>6;
  for (int tile = blockIdx.x; tile < ntiles; tile += gridDim.x){
    int e0 = tile<<6;
    for (int i = tid; i < 4096; i += 256){
      int el = i>>6, dd = i&63;
      int e = e0 + el;
      float y = 0.f;
      if (e < E){
        int dn = ei[E+e], sn = ei[e];
        float t = (P[(size_t)dn*64+dd] + Q[(size_t)sn*64+dd])*scS[dd] + ea[e]*c1S[dd] + bS[dd];
        y = fmaxf(t, 0.f);
      }
      ys[el][dd] = y;
    }
    __syncthreads();
    float acc[4][4];
    float4 b4 = *(const float4*)&b2S[dq*4];
    #pragma unroll
    for (int j=0;j<4;j++){ acc[j][0]=b4.x; acc[j][1]=b4.y; acc[j][2]=b4.z; acc[j][3]=b4.w; }
    for (int k=0;k<64;k+=4){
      float4 hv[4];
      #pragma unroll
      for (int j=0;j<4;j++) hv[j] = *(const float4*)&ys[rq*4+j][k];
      #pragma unroll
      for (int kk=0;kk<4;kk++){
        float4 wv = *(const float4*)&Ws[k+kk][dq*4];
        #pragma unroll
        for (int j=0;j<4;j++){
          float v = ((const float*)&hv[j])[kk];
          acc[j][0]+=v*wv.x; acc[j][1]+=v*wv.y; acc[j][2]+=v*wv.z; acc[j][3]+=v*wv.w;
        }
      }
    }
    #pragma unroll
    for (int j=0;j<4;j++){
      int e = e0 + rq*4 + j;
      if (e < E){
        if (STORE){
          ushort4 pk;
          pk.x = f2bf(acc[j][0]); pk.y = f2bf(acc[j][1]);
          pk.z = f2bf(acc[j][2]); pk.w = f2bf(acc[j][3]);
          *(ushort4*)(t2 + (size_t)e*64 + dq*4) = pk;
        }
        #pragma unroll
        for (int c=0;c<4;c++){ float v=acc[j][c]; ssum[c]+=v; ssq[c]+=v*v; }
      }
    }
    __syncthreads();
  }
  float* red = &ys[0][0];
  #pragma unroll
  for (int c=0;c<4;c++) red[rq*64 + dq*4 + c] = ssum[c];
  __syncthreads();
  if (tid < 64){
    float t=0.f;
    for (int r=0;r<16;r++) t += red[r*64+tid];
    atomicAdd(&stats2[tid], t);
  }
  __syncthreads();
  #pragma unroll
  for (int c=0;c<4;c++) red[rq*64 + dq*4 + c] = ssq[c];
  __syncthreads();
  if (tid < 64){
    float t=0.f;
    for (int r=0;r<16;r++) t += red[r*64+tid];
    atomicAdd(&stats2[64+tid], t);
  }
}

// ---- scatter from stored t2: y2 = relu(bn2(t2)); agg[dst] += y2 ----
__global__ __launch_bounds__(256) void k_sc(const u16* __restrict__ t2, const int* __restrict__ ei,
    const float* __restrict__ g2, const float* __restrict__ be2, const float* __restrict__ stats2,
    float* __restrict__ agg, int E, float invE){
  __shared__ float scS[64], shS[64];
  int tid = threadIdx.x;
  if (tid < 64){
    float m = stats2[tid]*invE;
    float v = stats2[64+tid]*invE - m*m;
    float sc = g2[tid]*rsqrtf(v+EPS);
    scS[tid] = sc; shS[tid] = be2[tid] - m*sc;
  }
  __syncthreads();
  int half = (tid>>5)&1;
  int d0 = (tid & 31)*2;
  int grp = tid >> 6;
  float sc0=scS[d0], sc1=scS[d0+1], sh0=shS[d0], sh1=shS[d0+1];
  for (int eb = blockIdx.x*8 + grp*2; eb < E; eb += gridDim.x*8){
    int e = eb + half;
    if (e < E){
      u32 pk = *(const u32*)(t2 + (size_t)e*64 + d0);
      float v0 = bf2f((u16)(pk & 0xffffu));
      float v1 = bf2f((u16)(pk >> 16));
      float y0 = fmaxf(v0*sc0 + sh0, 0.f);
      float y1 = fmaxf(v1*sc1 + sh1, 0.f);
      int dn = ei[E+e];
      atomicAdd(&agg[(size_t)dn*64 + d0], y0);
      atomicAdd(&agg[(size_t)dn*64 + d0 + 1], y1);
    }
  }
}

// ---- scatter with recompute (small-ws fallback): recompute y1, GEMM, bn2, scatter ----
__global__ __launch_bounds__(256) void k_sc_rec(const float* __restrict__ P, const float* __restrict__ Q,
    const float* __restrict__ ea, const int* __restrict__ ei,
    const float* __restrict__ c1, const float* __restrict__ b1,
    const float* __restrict__ g1, const float* __restrict__ be1, const float* __restrict__ stats1,
    const float* __restrict__ W2, const float* __restrict__ b2,
    const float* __restrict__ g2, const float* __restrict__ be2, const float* __restrict__ stats2,
    float* __restrict__ agg, int E, float invE){
  __shared__ float ys[64][68];
  __shared__ float Ws[64][64];
  __shared__ float scS[64], c1S[64], bS[64];
  __shared__ float s2S[64], h2S[64], b2S[64];
  int tid = threadIdx.x;
  if (tid < 64){
    float m = stats1[tid]*invE;
    float v = stats1[64+tid]*invE - m*m;
    float sc = g1[tid]*rsqrtf(v + EPS);
    scS[tid] = sc;
    c1S[tid] = c1[tid]*sc;
    bS[tid]  = b1[tid]*sc + be1[tid] - m*sc;
    float m2 = stats2[tid]*invE;
    float v2 = stats2[64+tid]*invE - m2*m2;
    float sc2 = g2[tid]*rsqrtf(v2+EPS);
    s2S[tid] = sc2; h2S[tid] = be2[tid] - m2*sc2;
    b2S[tid] = b2[tid];
  }
  for (int i=tid;i<4096;i+=256) Ws[i>>6][i&63] = W2[i];
  __syncthreads();
  int rq = tid>>4, dq = tid&15;
  int ntiles = (E+63)>>6;
  for (int tile = blockIdx.x; tile < ntiles; tile += gridDim.x){
    int e0 = tile<<6;
    for (int i = tid; i < 4096; i += 256){
      int el = i>>6, dd = i&63;
      int e = e0 + el;
      float y = 0.f;
      if (e < E){
        int dn = ei[E+e], sn = ei[e];
        float t = (P[(size_t)dn*64+dd] + Q[(size_t)sn*64+dd])*scS[dd] + ea[e]*c1S[dd] + bS[dd];
        y = fmaxf(t, 0.f);
      }
      ys[el][dd] = y;
    }
    __syncthreads();
    float acc[4][4];
    float4 b4 = *(const float4*)&b2S[dq*4];
    #pragma unroll
    for (int j=0;j<4;j++){ acc[j][0]=b4.x; acc[j][1]=b4.y; acc[j][2]=b4.z; acc[j][3]=b4.w; }
    for (int k=0;k<64;k+=4){
      float4 hv[4];
      #pragma unroll
      for (int j=0;j<4;j++) hv[j] = *(const float4*)&ys[rq*4+j][k];
      #pragma unroll
      for (int kk=0;kk<4;kk++){
        float4 wv = *(const float4*)&Ws[k+kk][dq*4];
        #pragma unroll
        for (int j=0;j<4;j++){
          float v = ((const float*)&hv[j])[kk];
          acc[j][0]+=v*wv.x; acc[j][1]+=v*wv.y; acc[j][2]+=v*wv.z; acc[j][3]+=v*wv.w;
        }
      }
    }
    float4 sc4 = *(const float4*)&s2S[dq*4];
    float4 sh4 = *(const float4*)&h2S[dq*4];
    #pragma unroll
    for (int j=0;j<4;j++){
      int e = e0 + rq*4 + j;
      if (e < E){
        int dn = ei[E+e];
        float y0 = fmaxf(acc[j][0]*sc4.x + sh4.x, 0.f);
        float y1 = fmaxf(acc[j][1]*sc4.y + sh4.y, 0.f);
        float y2 = fmaxf(acc[j][2]*sc4.z + sh4.z, 0.f);
        float y3 = fmaxf(acc[j][3]*sc4.w + sh4.w, 0.f);
        atomicAdd(&agg[(size_t)dn*64 + dq*4    ], y0);
        atomicAdd(&agg[(size_t)dn*64 + dq*4 + 1], y1);
        atomicAdd(&agg[(size_t)dn*64 + dq*4 + 2], y2);
        atomicAdd(&agg[(size_t)dn*64 + dq*4 + 3], y3);
      }
    }
    __syncthreads();
  }
}

// ---- upd layer1: tn = [h,agg] @ U1 + b ----
__global__ __launch_bounds__(256) void k_up1(const float* __restrict__ h, const float* __restrict__ agg,
    const float* __restrict__ U1, const float* __restrict__ b1u,
    float* __restrict__ tn, float* __restrict__ stats3, int N){
  __shared__ float ins[64][68];
  __shared__ float Ws[64][64];
  int tid = threadIdx.x;
  int rq = tid>>4, dq = tid&15;
  int row0 = blockIdx.x*64;
  float4 b4 = *(const float4*)(b1u + dq*4);
  float acc[4][4];
  #pragma unroll
  for (int j=0;j<4;j++){ acc[j][0]=b4.x; acc[j][1]=b4.y; acc[j][2]=b4.z; acc[j][3]=b4.w; }
  for (int p=0;p<2;p++){
    const float* src = p ? agg : h;
    for (int i=tid;i<4096;i+=256){
      int r=i>>6,k=i&63; int row=row0+r;
      ins[r][k] = (row<N)? src[(size_t)row*64+k] : 0.f;
    }
    for (int i=tid;i<4096;i+=256) Ws[i>>6][i&63] = U1[p*4096 + i];
    __syncthreads();
    for (int k=0;k<64;k+=4){
      float4 hv[4];
      #pragma unroll
      for (int j=0;j<4;j++) hv[j] = *(const float4*)&ins[rq*4+j][k];
      #pragma unroll
      for (int kk=0;kk<4;kk++){
        float4 wv = *(const float4*)&Ws[k+kk][dq*4];
        #pragma unroll
        for (int j=0;j<4;j++){
          float v = ((const float*)&hv[j])[kk];
          acc[j][0]+=v*wv.x; acc[j][1]+=v*wv.y; acc[j][2]+=v*wv.z; acc[j][3]+=v*wv.w;
        }
      }
    }
    __syncthreads();
  }
  float ssum[4]={}, ssq[4]={};
  #pragma unroll
  for (int j=0;j<4;j++){
    int row = row0 + rq*4 + j;
    if (row<N){
      *(float4*)(tn+(size_t)row*64+dq*4) = make_float4(acc[j][0],acc[j][1],acc[j][2],acc[j][3]);
      #pragma unroll
      for (int c=0;c<4;c++){ float v=acc[j][c]; ssum[c]+=v; ssq[c]+=v*v; }
    }
  }
  float* red = &ins[0][0];
  #pragma unroll
  for (int c=0;c<4;c++) red[rq*64 + dq*4 + c] = ssum[c];
  __syncthreads();
  if (tid < 64){
    float t=0.f; for (int r=0;r<16;r++) t += red[r*64+tid];
    atomicAdd(&stats3[tid], t);
  }
  __syncthreads();
  #pragma unroll
  for (int c=0;c<4;c++) red[rq*64 + dq*4 + c] = ssq[c];
  __syncthreads();
  if (tid < 64){
    float t=0.f; for (int r=0;r<16;r++) t += red[r*64+tid];
    atomicAdd(&stats3[64+tid], t);
  }
}

// ---- upd layer2: tn = relu(bn3(tn)) @ U2 + b2  (in place) ----
__global__ __launch_bounds__(256) void k_up2(float* __restrict__ tn,
    const float* __restrict__ g3, const float* __restrict__ be3, const float* __restrict__ stats3,
    const float* __restrict__ U2, const float* __restrict__ b2u,
    float* __restrict__ stats4, int N, float invN){
  __shared__ float ys[64][68];
  __shared__ float Ws[64][64];
  __shared__ float scS[64], shS[64], bS[64];
  int tid = threadIdx.x;
  if (tid < 64){
    float m = stats3[tid]*invN;
    float v = stats3[64+tid]*invN - m*m;
    float sc = g3[tid]*rsqrtf(v+EPS);
    scS[tid] = sc; shS[tid] = be3[tid] - m*sc; bS[tid] = b2u[tid];
  }
  for (int i=tid;i<4096;i+=256) Ws[i>>6][i&63] = U2[i];
  int row0 = blockIdx.x*64;
  __syncthreads();
  for (int i=tid;i<4096;i+=256){
    int r=i>>6,k=i&63; int row=row0+r;
    float y = 0.f;
    if (row<N) y = fmaxf(tn[(size_t)row*64+k]*scS[k] + shS[k], 0.f);
    ys[r][k] = y;
  }
  __syncthreads();
  int rq = tid>>4, dq = tid&15;
  float4 b4 = *(const float4*)&bS[dq*4];
  float acc[4][4];
  #pragma unroll
  for (int j=0;j<4;j++){ acc[j][0]=b4.x; acc[j][1]=b4.y; acc[j][2]=b4.z; acc[j][3]=b4.w; }
  for (int k=0;k<64;k+=4){
    float4 hv[4];
    #pragma unroll
    for (int j=0;j<4;j++) hv[j] = *(const float4*)&ys[rq*4+j][k];
    #pragma unroll
    for (int kk=0;kk<4;kk++){
      float4 wv = *(const float4*)&Ws[k+kk][dq*4];
      #pragma unroll
      for (int j=0;j<4;j++){
        float v = ((const float*)&hv[j])[kk];
        acc[j][0]+=v*wv.x; acc[j][1]+=v*wv.y; acc[j][2]+=v*wv.z; acc[j][3]+=v*wv.w;
      }
    }
  }
  float ssum[4]={}, ssq[4]={};
  #pragma unroll
  for (int j=0;j<4;j++){
    int row = row0 + rq*4 + j;
    if (row<N){
      *(float4*)(tn+(size_t)row*64+dq*4) = make_float4(acc[j][0],acc[j][1],acc[j][2],acc[j][3]);
      #pragma unroll
      for (int c=0;c<4;c++){ float v=acc[j][c]; ssum[c]+=v; ssq[c]+=v*v; }
    }
  }
  __syncthreads();
  float* red = &ys[0][0];
  #pragma unroll
  for (int c=0;c<4;c++) red[rq*64 + dq*4 + c] = ssum[c];
  __syncthreads();
  if (tid < 64){
    float t=0.f; for (int r=0;r<16;r++) t += red[r*64+tid];
    atomicAdd(&stats4[tid], t);
  }
  __syncthreads();
  #pragma unroll
  for (int c=0;c<4;c++) red[rq*64 + dq*4 + c] = ssq[c];
  __syncthreads();
  if (tid < 64){
    float t=0.f; for (int r=0;r<16;r++) t += red[r*64+tid];
    atomicAdd(&stats4[64+tid], t);
  }
}

// ---- residual + next-layer P,Q: h += relu(bn4(tn)); P=h@A, Q=h@B ----
__global__ __launch_bounds__(256) void k_res_pq(float* __restrict__ h, const float* __restrict__ tn,
    const float* __restrict__ g4, const float* __restrict__ be4, const float* __restrict__ stats4,
    const float* __restrict__ A, const float* __restrict__ B,
    float* __restrict__ P, float* __restrict__ Q, int N, float invN){
  __shared__ float hs[64][68];
  __shared__ float As[64][64];
  __shared__ float Bs[64][64];
  __shared__ float scS[64], shS[64];
  int tid = threadIdx.x;
  if (tid < 64){
    float m = stats4[tid]*invN;
    float v = stats4[64+tid]*invN - m*m;
    float sc = g4[tid]*rsqrtf(v+EPS);
    scS[tid] = sc; shS[tid] = be4[tid] - m*sc;
  }
  for (int i = tid; i < 4096; i += 256){ As[i>>6][i&63] = A[i]; Bs[i>>6][i&63] = B[i]; }
  int row0 = blockIdx.x*64;
  __syncthreads();
  for (int i = tid; i < 4096; i += 256){
    int r = i>>6, k = i&63; int row = row0+r;
    float hv = 0.f;
    if (row<N){
      hv = h[(size_t)row*64+k] + fmaxf(tn[(size_t)row*64+k]*scS[k] + shS[k], 0.f);
      h[(size_t)row*64+k] = hv;
    }
    hs[r][k] = hv;
  }
  __syncthreads();
  int rq = tid>>4, dq = tid&15;
  float ap[4][4]={}, aq[4][4]={};
  for (int k=0;k<64;k+=4){
    float4 hv[4];
    #pragma unroll
    for (int j=0;j<4;j++) hv[j] = *(const float4*)&hs[rq*4+j][k];
    #pragma unroll
    for (int kk=0;kk<4;kk++){
      float4 av = *(const float4*)&As[k+kk][dq*4];
      float4 bv = *(const float4*)&Bs[k+kk][dq*4];
      #pragma unroll
      for (int j=0;j<4;j++){
        float v = ((const float*)&hv[j])[kk];
        ap[j][0]+=v*av.x; ap[j][1]+=v*av.y; ap[j][2]+=v*av.z; ap[j][3]+=v*av.w;
        aq[j][0]+=v*bv.x; aq[j][1]+=v*bv.y; aq[j][2]+=v*bv.z; aq[j][3]+=v*bv.w;
      }
    }
  }
  #pragma unroll
  for (int j=0;j<4;j++){
    int row = row0 + rq*4 + j;
    if (row<N){
      *(float4*)(P+(size_t)row*64+dq*4) = make_float4(ap[j][0],ap[j][1],ap[j][2],ap[j][3]);
      *(float4*)(Q+(size_t)row*64+dq*4) = make_float4(aq[j][0],aq[j][1],aq[j][2],aq[j][3]);
    }
  }
}

// ---- final: h += relu(bn4(tn)); out = relu(h@Wp+bp) @ Wo + bo ----
__global__ __launch_bounds__(256) void k_res_head(const float* __restrict__ h, const float* __restrict__ tn,
    const float* __restrict__ g4, const float* __restrict__ be4, const float* __restrict__ stats4,
    const float* __restrict__ Wp, const float* __restrict__ bp,
    const float* __restrict__ Wo, const float* __restrict__ bo,
    float* __restrict__ out, int N, float invN){
  __shared__ float hs[64][68];
  __shared__ float Wps[64][64];
  __shared__ float ps[64][68];
  __shared__ float Wos[64][16];
  __shared__ float scS[64], shS[64];
  int tid = threadIdx.x;
  if (tid < 64){
    float m = stats4[tid]*invN;
    float v = stats4[64+tid]*invN - m*m;
    float sc = g4[tid]*rsqrtf(v+EPS);
    scS[tid] = sc; shS[tid] = be4[tid] - m*sc;
  }
  for (int i=tid;i<4096;i+=256) Wps[i>>6][i&63] = Wp[i];
  for (int i=tid;i<1024;i+=256) Wos[i>>4][i&15] = Wo[i];
  int row0 = blockIdx.x*64;
  __syncthreads();
  for (int i = tid; i < 4096; i += 256){
    int r = i>>6, k = i&63; int row = row0+r;
    float hv = 0.f;
    if (row<N)
      hv = h[(size_t)row*64+k] + fmaxf(tn[(size_t)row*64+k]*scS[k] + shS[k], 0.f);
    hs[r][k] = hv;
  }
  __syncthreads();
  int rq = tid>>4, dq = tid&15;
  float4 b4 = *(const float4*)(bp + dq*4);
  float acc[4][4];
  #pragma unroll
  for (int j=0;j<4;j++){ acc[j][0]=b4.x; acc[j][1]=b4.y; acc[j][2]=b4.z; acc[j][3]=b4.w; }
  for (int k=0;k<64;k+=4){
    float4 hv[4];
    #pragma unroll
    for (int j=0;j<4;j++) hv[j] = *(const float4*)&hs[rq*4+j][k];
    #pragma unroll
    for (int kk=0;kk<4;kk++){
      float4 wv = *(const float4*)&Wps[k+kk][dq*4];
      #pragma unroll
      for (int j=0;j<4;j++){
        float v = ((const float*)&hv[j])[kk];
        acc[j][0]+=v*wv.x; acc[j][1]+=v*wv.y; acc[j][2]+=v*wv.z; acc[j][3]+=v*wv.w;
      }
    }
  }
  #pragma unroll
  for (int j=0;j<4;j++){
    *(float4*)&ps[rq*4+j][dq*4] = make_float4(fmaxf(acc[j][0],0.f), fmaxf(acc[j][1],0.f),
                                              fmaxf(acc[j][2],0.f), fmaxf(acc[j][3],0.f));
  }
  __syncthreads();
  int f = tid & 15;
  float bof = bo[f];
  float acc2[4] = {bof, bof, bof, bof};
  for (int k=0;k<64;k++){
    float wv = Wos[k][f];
    #pragma unroll
    for (int j=0;j<4;j++) acc2[j] += ps[rq*4+j][k]*wv;
  }
  #pragma unroll
  for (int j=0;j<4;j++){
    int row = row0 + rq*4 + j;
    if (row<N) out[(size_t)row*16 + f] = acc2[j];
  }
}

extern "C" void kernel_launch(void* const* d_in, const int* in_sizes, int n_in,
                              void* d_out, int out_size, void* d_ws, size_t ws_size,
                              hipStream_t stream){
  const float* x    = (const float*)d_in[0];
  const float* eatt = (const float*)d_in[1];
  const float* Win  = (const float*)d_in[2];
  const float* bin  = (const float*)d_in[3];
  const float* mW1  = (const float*)d_in[4];
  const float* mb1  = (const float*)d_in[5];
  const float* mg1  = (const float*)d_in[6];
  const float* mbe1 = (const float*)d_in[7];
  const float* mW2  = (const float*)d_in[8];
  const float* mb2  = (const float*)d_in[9];
  const float* mg2  = (const float*)d_in[10];
  const float* mbe2 = (const float*)d_in[11];
  const float* uW1  = (const float*)d_in[12];
  const float* ub1  = (const float*)d_in[13];
  const float* ug1  = (const float*)d_in[14];
  const float* ube1 = (const float*)d_in[15];
  const float* uW2  = (const float*)d_in[16];
  const float* ub2  = (const float*)d_in[17];
  const float* ug2  = (const float*)d_in[18];
  const float* ube2 = (const float*)d_in[19];
  const float* predW = (const float*)d_in[24];
  const float* predb = (const float*)d_in[25];
  const float* poutW = (const float*)d_in[26];
  const float* poutb = (const float*)d_in[27];
  const int*   ei    = (const int*)d_in[28];

  const int N = in_sizes[0] / 18;
  const int E = in_sizes[1];

  size_t nodeB = (size_t)N * 64 * sizeof(float);
  size_t t2B   = (size_t)E * 64 * sizeof(u16);
  size_t statsB = 16 * 128 * sizeof(float);

  // Plan A: h,P,Q + t2 (agg aliases P, tn aliases Q) -> 3*nodeB + t2B + statsB
  // Plan B: h,P,Q,agg (tn aliases P); scatter recomputes GEMM -> 4*nodeB + statsB
  bool planA = ws_size >= 3*nodeB + t2B + statsB;

  char* w = (char*)d_ws;
  float* h = (float*)w; w += nodeB;
  float* P = (float*)w; w += nodeB;
  float* Q = (float*)w; w += nodeB;
  u16*  t2 = nullptr;
  float* agg;
  float* tn;
  float* stats;
  if (planA){
    t2 = (u16*)w; w += t2B;
    stats = (float*)w;
    agg = P;   // P dead after k_m2, rewritten by k_res_pq
    tn  = Q;   // Q dead after k_m2; k_res_pq reads tn=Q block-locally before writing Q
  } else {
    agg = (float*)w; w += nodeB;
    stats = (float*)w;
    tn = P;    // P dead after k_sc_rec
  }

  hipMemsetAsync(stats, 0, statsB, stream);

  int nb = (N + 63)/64;
  float invE = 1.0f/(float)E, invN = 1.0f/(float)N;

  k_in<<<nb, 256, 0, stream>>>(x, Win, bin, h, N);
  k_pq<<<nb, 256, 0, stream>>>(h, mW1, mW1 + 4096, P, Q, N);

  for (int l = 0; l < 4; ++l){
    float* s1 = stats + (l*4+0)*128;
    float* s2 = stats + (l*4+1)*128;
    float* s3 = stats + (l*4+2)*128;
    float* s4 = stats + (l*4+3)*128;
    const float* A  = mW1 + (size_t)l*8256;
    const float* c1 = A + 8192;
    k_s1<<<2048, 256, 0, stream>>>(P, Q, eatt, ei, c1, mb1 + l*64, s1, E);
    if (planA){
      k_m2<1><<<1024, 256, 0, stream>>>(P, Q, eatt, ei, c1, mb1 + l*64, mg1 + l*64, mbe1 + l*64,
                                        s1, mW2 + (size_t)l*4096, mb2 + l*64, t2, s2, E, invE);
      hipMemsetAsync(agg, 0, nodeB, stream);
      k_sc<<<2048, 256, 0, stream>>>(t2, ei, mg2 + l*64, mbe2 + l*64, s2, agg, E, invE);
    } else {
      k_m2<0><<<1024, 256, 0, stream>>>(P, Q, eatt, ei, c1, mb1 + l*64, mg1 + l*64, mbe1 + l*64,
                                        s1, mW2 + (size_t)l*4096, mb2 + l*64, t2, s2, E, invE);
      hipMemsetAsync(agg, 0, nodeB, stream);
      k_sc_rec<<<1024, 256, 0, stream>>>(P, Q, eatt, ei, c1, mb1 + l*64, mg1 + l*64, mbe1 + l*64,
                                         s1, mW2 + (size_t)l*4096, mb2 + l*64,
                                         mg2 + l*64, mbe2 + l*64, s2, agg, E, invE);
    }
    k_up1<<<nb, 256, 0, stream>>>(h, agg, uW1 + (size_t)l*8192, ub1 + l*64, tn, s3, N);
    k_up2<<<nb, 256, 0, stream>>>(tn, ug1 + l*64, ube1 + l*64, s3, uW2 + (size_t)l*4096,
                                  ub2 + l*64, s4, N, invN);
    if (l < 3){
      const float* An = mW1 + (size_t)(l+1)*8256;
      k_res_pq<<<nb, 256, 0, stream>>>(h, tn, ug2 + l*64, ube2 + l*64, s4,
                                       An, An + 4096, P, Q, N, invN);
    } else {
      k_res_head<<<nb, 256, 0, stream>>>(h, tn, ug2 + l*64, ube2 + l*64, s4,
                                         predW, predb, poutW, poutb, (float*)d_out, N, invN);
    }
  }
}

// Round 3
// 4902.573 us; speedup vs baseline: 1.5026x; 1.5026x over previous
//
#include <hip/hip_runtime.h>
#include <hip/hip_fp16.h>

typedef unsigned short u16;
typedef unsigned int u32;
typedef __attribute__((ext_vector_type(8))) unsigned short us8;

#define EPS 1e-5f

__device__ __forceinline__ float h2f(u16 h){ __half v; *(u16*)&v = h; return __half2float(v); }
__device__ __forceinline__ u16 f2h(float f){ __half v = __float2half(f); return *(u16*)&v; }

// ---------------- input projection: h = x @ W_in + b_in ----------------
__global__ __launch_bounds__(256) void k_in(const float* __restrict__ x,
    const float* __restrict__ Win, const float* __restrict__ bin,
    float* __restrict__ h, int N){
  __shared__ float Ws[18][64];
  __shared__ float xs[64][20];
  int tid = threadIdx.x;
  for (int i = tid; i < 18*64; i += 256) Ws[i>>6][i&63] = Win[i];
  int row0 = blockIdx.x * 64;
  for (int i = tid; i < 64*18; i += 256){
    int r = i/18, k = i - r*18;
    int row = row0 + r;
    xs[r][k] = (row < N) ? x[(size_t)row*18 + k] : 0.f;
  }
  __syncthreads();
  int rq = tid >> 4, dq = tid & 15;
  float4 b4 = *(const float4*)(bin + dq*4);
  float acc[4][4];
  #pragma unroll
  for (int j=0;j<4;j++){ acc[j][0]=b4.x; acc[j][1]=b4.y; acc[j][2]=b4.z; acc[j][3]=b4.w; }
  for (int k=0;k<18;k++){
    float4 wv = *(const float4*)&Ws[k][dq*4];
    #pragma unroll
    for (int j=0;j<4;j++){
      float v = xs[rq*4+j][k];
      acc[j][0]+=v*wv.x; acc[j][1]+=v*wv.y; acc[j][2]+=v*wv.z; acc[j][3]+=v*wv.w;
    }
  }
  #pragma unroll
  for (int j=0;j<4;j++){
    int row = row0 + rq*4 + j;
    if (row < N)
      *(float4*)(h + (size_t)row*64 + dq*4) = make_float4(acc[j][0],acc[j][1],acc[j][2],acc[j][3]);
  }
}

// ---------------- P = h@A, Q = h@B (A,B are 64x64) ----------------
__global__ __launch_bounds__(256) void k_pq(const float* __restrict__ h,
    const float* __restrict__ A, const float* __restrict__ B,
    float* __restrict__ P, float* __restrict__ Q, int N){
  __shared__ float hs[64][68];
  __shared__ float As[64][64];
  __shared__ float Bs[64][64];
  int tid = threadIdx.x;
  for (int i = tid; i < 4096; i += 256){ As[i>>6][i&63] = A[i]; Bs[i>>6][i&63] = B[i]; }
  int row0 = blockIdx.x*64;
  for (int i = tid; i < 4096; i += 256){
    int r = i>>6, k = i&63; int row = row0+r;
    hs[r][k] = (row<N)? h[(size_t)row*64+k] : 0.f;
  }
  __syncthreads();
  int rq = tid>>4, dq = tid&15;
  float ap[4][4]={}, aq[4][4]={};
  for (int k=0;k<64;k+=4){
    float4 hv[4];
    #pragma unroll
    for (int j=0;j<4;j++) hv[j] = *(const float4*)&hs[rq*4+j][k];
    #pragma unroll
    for (int kk=0;kk<4;kk++){
      float4 av = *(const float4*)&As[k+kk][dq*4];
      float4 bv = *(const float4*)&Bs[k+kk][dq*4];
      #pragma unroll
      for (int j=0;j<4;j++){
        float v = ((const float*)&hv[j])[kk];
        ap[j][0]+=v*av.x; ap[j][1]+=v*av.y; ap[j][2]+=v*av.z; ap[j][3]+=v*av.w;
        aq[j][0]+=v*bv.x; aq[j][1]+=v*bv.y; aq[j][2]+=v*bv.z; aq[j][3]+=v*bv.w;
      }
    }
  }
  #pragma unroll
  for (int j=0;j<4;j++){
    int row = row0 + rq*4 + j;
    if (row<N){
      *(float4*)(P+(size_t)row*64+dq*4) = make_float4(ap[j][0],ap[j][1],ap[j][2],ap[j][3]);
      *(float4*)(Q+(size_t)row*64+dq*4) = make_float4(aq[j][0],aq[j][1],aq[j][2],aq[j][3]);
    }
  }
}

// ------- gather ONCE: t = P[dst]+Q[src]+ea*c1+b1 -> fp16 store + BN1 stats -------
__global__ __launch_bounds__(256) void k_t1(const float* __restrict__ P, const float* __restrict__ Q,
    const float* __restrict__ ea, const int* __restrict__ ei,
    const float* __restrict__ c1, const float* __restrict__ b1,
    u16* __restrict__ t, float* __restrict__ stats, int E){
  int tid = threadIdx.x;
  int d = tid & 63, w = tid >> 6;
  float cv = c1[d], bv = b1[d];
  float s = 0.f, sq = 0.f;
  for (int e = blockIdx.x*4 + w; e < E; e += gridDim.x*4){
    int dn = ei[E+e], sn = ei[e];
    float tt = P[(size_t)dn*64+d] + Q[(size_t)sn*64+d] + ea[e]*cv + bv;
    t[(size_t)e*64 + d] = f2h(tt);
    s += tt; sq += tt*tt;
  }
  __shared__ float sS[4][64], qS[4][64];
  sS[w][d] = s; qS[w][d] = sq;
  __syncthreads();
  if (tid < 64){
    float ts = sS[0][tid]+sS[1][tid]+sS[2][tid]+sS[3][tid];
    float tq = qS[0][tid]+qS[1][tid]+qS[2][tid]+qS[3][tid];
    atomicAdd(&stats[tid], ts);
    atomicAdd(&stats[64+tid], tq);
  }
}

// ---- streaming msg layer2: y1 = relu(bn1(t)); t2 = y1@W2+b2 (in place, fp16) + stats2 ----
__global__ __launch_bounds__(256) void k_m2s(u16* __restrict__ t,
    const float* __restrict__ g1, const float* __restrict__ be1, const float* __restrict__ stats1,
    const float* __restrict__ W2, const float* __restrict__ b2,
    float* __restrict__ stats2, int E, float invE){
  __shared__ float ys[64][68];
  __shared__ float Ws[64][64];
  __shared__ float scS[64], shS[64], b2S[64];
  int tid = threadIdx.x;
  if (tid < 64){
    float m = stats1[tid]*invE;
    float v = stats1[64+tid]*invE - m*m;
    float sc = g1[tid]*rsqrtf(v + EPS);
    scS[tid] = sc; shS[tid] = be1[tid] - m*sc;
    b2S[tid] = b2[tid];
  }
  for (int i=tid;i<4096;i+=256) Ws[i>>6][i&63] = W2[i];
  __syncthreads();
  int rq = tid>>4, dq = tid&15;
  int sr = tid>>2, sq4 = (tid&3)*16;     // staging: row 0..63, 16 dims
  float ssum[4]={}, ssq[4]={};
  int ntiles = (E+63)>>6;
  for (int tile = blockIdx.x; tile < ntiles; tile += gridDim.x){
    int e0 = tile<<6;
    {
      int e = e0 + sr;
      if (e < E){
        const u16* src = t + (size_t)e*64 + sq4;
        us8 a = *(const us8*)src;
        us8 b = *(const us8*)(src + 8);
        #pragma unroll
        for (int j=0;j<8;j++){
          int dd = sq4 + j;
          ys[sr][dd] = fmaxf(h2f(a[j])*scS[dd] + shS[dd], 0.f);
        }
        #pragma unroll
        for (int j=0;j<8;j++){
          int dd = sq4 + 8 + j;
          ys[sr][dd] = fmaxf(h2f(b[j])*scS[dd] + shS[dd], 0.f);
        }
      } else {
        #pragma unroll
        for (int j=0;j<16;j++) ys[sr][sq4+j] = 0.f;
      }
    }
    __syncthreads();
    float acc[4][4];
    float4 b4 = *(const float4*)&b2S[dq*4];
    #pragma unroll
    for (int j=0;j<4;j++){ acc[j][0]=b4.x; acc[j][1]=b4.y; acc[j][2]=b4.z; acc[j][3]=b4.w; }
    for (int k=0;k<64;k+=4){
      float4 hv[4];
      #pragma unroll
      for (int j=0;j<4;j++) hv[j] = *(const float4*)&ys[rq*4+j][k];
      #pragma unroll
      for (int kk=0;kk<4;kk++){
        float4 wv = *(const float4*)&Ws[k+kk][dq*4];
        #pragma unroll
        for (int j=0;j<4;j++){
          float v = ((const float*)&hv[j])[kk];
          acc[j][0]+=v*wv.x; acc[j][1]+=v*wv.y; acc[j][2]+=v*wv.z; acc[j][3]+=v*wv.w;
        }
      }
    }
    #pragma unroll
    for (int j=0;j<4;j++){
      int e = e0 + rq*4 + j;
      if (e < E){
        ushort4 pk;
        pk.x = f2h(acc[j][0]); pk.y = f2h(acc[j][1]);
        pk.z = f2h(acc[j][2]); pk.w = f2h(acc[j][3]);
        *(ushort4*)(t + (size_t)e*64 + dq*4) = pk;
        #pragma unroll
        for (int c=0;c<4;c++){ float v=acc[j][c]; ssum[c]+=v; ssq[c]+=v*v; }
      }
    }
    __syncthreads();
  }
  float* red = &ys[0][0];
  #pragma unroll
  for (int c=0;c<4;c++) red[rq*64 + dq*4 + c] = ssum[c];
  __syncthreads();
  if (tid < 64){
    float tt=0.f;
    for (int r=0;r<16;r++) tt += red[r*64+tid];
    atomicAdd(&stats2[tid], tt);
  }
  __syncthreads();
  #pragma unroll
  for (int c=0;c<4;c++) red[rq*64 + dq*4 + c] = ssq[c];
  __syncthreads();
  if (tid < 64){
    float tt=0.f;
    for (int r=0;r<16;r++) tt += red[r*64+tid];
    atomicAdd(&stats2[64+tid], tt);
  }
}

// ---- scatter from stored t2 (fp16): y2 = relu(bn2(t2)); agg[dst] += y2 ----
__global__ __launch_bounds__(256) void k_sc(const u16* __restrict__ t2, const int* __restrict__ ei,
    const float* __restrict__ g2, const float* __restrict__ be2, const float* __restrict__ stats2,
    float* __restrict__ agg, int E, float invE){
  __shared__ float scS[64], shS[64];
  int tid = threadIdx.x;
  if (tid < 64){
    float m = stats2[tid]*invE;
    float v = stats2[64+tid]*invE - m*m;
    float sc = g2[tid]*rsqrtf(v+EPS);
    scS[tid] = sc; shS[tid] = be2[tid] - m*sc;
  }
  __syncthreads();
  int half = (tid>>5)&1;
  int d0 = (tid & 31)*2;
  int grp = tid >> 6;
  float sc0=scS[d0], sc1=scS[d0+1], sh0=shS[d0], sh1=shS[d0+1];
  for (int eb = blockIdx.x*8 + grp*2; eb < E; eb += gridDim.x*8){
    int e = eb + half;
    if (e < E){
      u32 pk = *(const u32*)(t2 + (size_t)e*64 + d0);
      float v0 = h2f((u16)(pk & 0xffffu));
      float v1 = h2f((u16)(pk >> 16));
      float y0 = fmaxf(v0*sc0 + sh0, 0.f);
      float y1 = fmaxf(v1*sc1 + sh1, 0.f);
      int dn = ei[E+e];
      atomicAdd(&agg[(size_t)dn*64 + d0], y0);
      atomicAdd(&agg[(size_t)dn*64 + d0 + 1], y1);
    }
  }
}

// ======== Plan-B fallback (small ws): stats pass + recompute scatter ========
__global__ __launch_bounds__(256) void k_s1(const float* __restrict__ P, const float* __restrict__ Q,
    const float* __restrict__ ea, const int* __restrict__ ei,
    const float* __restrict__ c1, const float* __restrict__ b1,
    float* __restrict__ stats, int E){
  int tid = threadIdx.x;
  int d = tid & 63, w = tid >> 6;
  float cv = c1[d], bv = b1[d];
  float s = 0.f, sq = 0.f;
  for (int e = blockIdx.x*4 + w; e < E; e += gridDim.x*4){
    int dn = ei[E+e], sn = ei[e];
    float t = P[(size_t)dn*64+d] + Q[(size_t)sn*64+d] + ea[e]*cv + bv;
    s += t; sq += t*t;
  }
  __shared__ float sS[4][64], qS[4][64];
  sS[w][d] = s; qS[w][d] = sq;
  __syncthreads();
  if (tid < 64){
    float ts = sS[0][tid]+sS[1][tid]+sS[2][tid]+sS[3][tid];
    float tq = qS[0][tid]+qS[1][tid]+qS[2][tid]+qS[3][tid];
    atomicAdd(&stats[tid], ts);
    atomicAdd(&stats[64+tid], tq);
  }
}

__global__ __launch_bounds__(256) void k_m2b(const float* __restrict__ P, const float* __restrict__ Q,
    const float* __restrict__ ea, const int* __restrict__ ei,
    const float* __restrict__ c1, const float* __restrict__ b1,
    const float* __restrict__ g1, const float* __restrict__ be1,
    const float* __restrict__ stats1,
    const float* __restrict__ W2, const float* __restrict__ b2,
    float* __restrict__ stats2, int E, float invE){
  __shared__ float ys[64][68];
  __shared__ float Ws[64][64];
  __shared__ float scS[64], c1S[64], bS[64], b2S[64];
  int tid = threadIdx.x;
  if (tid < 64){
    float m = stats1[tid]*invE;
    float v = stats1[64+tid]*invE - m*m;
    float sc = g1[tid]*rsqrtf(v + EPS);
    float sh = be1[tid] - m*sc;
    scS[tid] = sc;
    c1S[tid] = c1[tid]*sc;
    bS[tid]  = b1[tid]*sc + sh;
    b2S[tid] = b2[tid];
  }
  for (int i=tid;i<4096;i+=256) Ws[i>>6][i&63] = W2[i];
  __syncthreads();
  int rq = tid>>4, dq = tid&15;
  float ssum[4]={}, ssq[4]={};
  int ntiles = (E+63)>>6;
  for (int tile = blockIdx.x; tile < ntiles; tile += gridDim.x){
    int e0 = tile<<6;
    for (int i = tid; i < 4096; i += 256){
      int el = i>>6, dd = i&63;
      int e = e0 + el;
      float y = 0.f;
      if (e < E){
        int dn = ei[E+e], sn = ei[e];
        float t = (P[(size_t)dn*64+dd] + Q[(size_t)sn*64+dd])*scS[dd] + ea[e]*c1S[dd] + bS[dd];
        y = fmaxf(t, 0.f);
      }
      ys[el][dd] = y;
    }
    __syncthreads();
    float acc[4][4];
    float4 b4 = *(const float4*)&b2S[dq*4];
    #pragma unroll
    for (int j=0;j<4;j++){ acc[j][0]=b4.x; acc[j][1]=b4.y; acc[j][2]=b4.z; acc[j][3]=b4.w; }
    for (int k=0;k<64;k+=4){
      float4 hv[4];
      #pragma unroll
      for (int j=0;j<4;j++) hv[j] = *(const float4*)&ys[rq*4+j][k];
      #pragma unroll
      for (int kk=0;kk<4;kk++){
        float4 wv = *(const float4*)&Ws[k+kk][dq*4];
        #pragma unroll
        for (int j=0;j<4;j++){
          float v = ((const float*)&hv[j])[kk];
          acc[j][0]+=v*wv.x; acc[j][1]+=v*wv.y; acc[j][2]+=v*wv.z; acc[j][3]+=v*wv.w;
        }
      }
    }
    #pragma unroll
    for (int j=0;j<4;j++){
      int e = e0 + rq*4 + j;
      if (e < E){
        #pragma unroll
        for (int c=0;c<4;c++){ float v=acc[j][c]; ssum[c]+=v; ssq[c]+=v*v; }
      }
    }
    __syncthreads();
  }
  float* red = &ys[0][0];
  #pragma unroll
  for (int c=0;c<4;c++) red[rq*64 + dq*4 + c] = ssum[c];
  __syncthreads();
  if (tid < 64){
    float t=0.f;
    for (int r=0;r<16;r++) t += red[r*64+tid];
    atomicAdd(&stats2[tid], t);
  }
  __syncthreads();
  #pragma unroll
  for (int c=0;c<4;c++) red[rq*64 + dq*4 + c] = ssq[c];
  __syncthreads();
  if (tid < 64){
    float t=0.f;
    for (int r=0;r<16;r++) t += red[r*64+tid];
    atomicAdd(&stats2[64+tid], t);
  }
}

__global__ __launch_bounds__(256) void k_sc_rec(const float* __restrict__ P, const float* __restrict__ Q,
    const float* __restrict__ ea, const int* __restrict__ ei,
    const float* __restrict__ c1, const float* __restrict__ b1,
    const float* __restrict__ g1, const float* __restrict__ be1, const float* __restrict__ stats1,
    const float* __restrict__ W2, const float* __restrict__ b2,
    const float* __restrict__ g2, const float* __restrict__ be2, const float* __restrict__ stats2,
    float* __restrict__ agg, int E, float invE){
  __shared__ float ys[64][68];
  __shared__ float Ws[64][64];
  __shared__ float scS[64], c1S[64], bS[64];
  __shared__ float s2S[64], h2S[64], b2S[64];
  int tid = threadIdx.x;
  if (tid < 64){
    float m = stats1[tid]*invE;
    float v = stats1[64+tid]*invE - m*m;
    float sc = g1[tid]*rsqrtf(v + EPS);
    scS[tid] = sc;
    c1S[tid] = c1[tid]*sc;
    bS[tid]  = b1[tid]*sc + be1[tid] - m*sc;
    float m2 = stats2[tid]*invE;
    float v2 = stats2[64+tid]*invE - m2*m2;
    float sc2 = g2[tid]*rsqrtf(v2+EPS);
    s2S[tid] = sc2; h2S[tid] = be2[tid] - m2*sc2;
    b2S[tid] = b2[tid];
  }
  for (int i=tid;i<4096;i+=256) Ws[i>>6][i&63] = W2[i];
  __syncthreads();
  int rq = tid>>4, dq = tid&15;
  int ntiles = (E+63)>>6;
  for (int tile = blockIdx.x; tile < ntiles; tile += gridDim.x){
    int e0 = tile<<6;
    for (int i = tid; i < 4096; i += 256){
      int el = i>>6, dd = i&63;
      int e = e0 + el;
      float y = 0.f;
      if (e < E){
        int dn = ei[E+e], sn = ei[e];
        float t = (P[(size_t)dn*64+dd] + Q[(size_t)sn*64+dd])*scS[dd] + ea[e]*c1S[dd] + bS[dd];
        y = fmaxf(t, 0.f);
      }
      ys[el][dd] = y;
    }
    __syncthreads();
    float acc[4][4];
    float4 b4 = *(const float4*)&b2S[dq*4];
    #pragma unroll
    for (int j=0;j<4;j++){ acc[j][0]=b4.x; acc[j][1]=b4.y; acc[j][2]=b4.z; acc[j][3]=b4.w; }
    for (int k=0;k<64;k+=4){
      float4 hv[4];
      #pragma unroll
      for (int j=0;j<4;j++) hv[j] = *(const float4*)&ys[rq*4+j][k];
      #pragma unroll
      for (int kk=0;kk<4;kk++){
        float4 wv = *(const float4*)&Ws[k+kk][dq*4];
        #pragma unroll
        for (int j=0;j<4;j++){
          float v = ((const float*)&hv[j])[kk];
          acc[j][0]+=v*wv.x; acc[j][1]+=v*wv.y; acc[j][2]+=v*wv.z; acc[j][3]+=v*wv.w;
        }
      }
    }
    float4 sc4 = *(const float4*)&s2S[dq*4];
    float4 sh4 = *(const float4*)&h2S[dq*4];
    #pragma unroll
    for (int j=0;j<4;j++){
      int e = e0 + rq*4 + j;
      if (e < E){
        int dn = ei[E+e];
        float y0 = fmaxf(acc[j][0]*sc4.x + sh4.x, 0.f);
        float y1 = fmaxf(acc[j][1]*sc4.y + sh4.y, 0.f);
        float y2 = fmaxf(acc[j][2]*sc4.z + sh4.z, 0.f);
        float y3 = fmaxf(acc[j][3]*sc4.w + sh4.w, 0.f);
        atomicAdd(&agg[(size_t)dn*64 + dq*4    ], y0);
        atomicAdd(&agg[(size_t)dn*64 + dq*4 + 1], y1);
        atomicAdd(&agg[(size_t)dn*64 + dq*4 + 2], y2);
        atomicAdd(&agg[(size_t)dn*64 + dq*4 + 3], y3);
      }
    }
    __syncthreads();
  }
}

// ---- upd layer1: tn = [h,agg] @ U1 + b ----
__global__ __launch_bounds__(256) void k_up1(const float* __restrict__ h, const float* __restrict__ agg,
    const float* __restrict__ U1, const float* __restrict__ b1u,
    float* __restrict__ tn, float* __restrict__ stats3, int N){
  __shared__ float ins[64][68];
  __shared__ float Ws[64][64];
  int tid = threadIdx.x;
  int rq = tid>>4, dq = tid&15;
  int row0 = blockIdx.x*64;
  float4 b4 = *(const float4*)(b1u + dq*4);
  float acc[4][4];
  #pragma unroll
  for (int j=0;j<4;j++){ acc[j][0]=b4.x; acc[j][1]=b4.y; acc[j][2]=b4.z; acc[j][3]=b4.w; }
  for (int p=0;p<2;p++){
    const float* src = p ? agg : h;
    for (int i=tid;i<4096;i+=256){
      int r=i>>6,k=i&63; int row=row0+r;
      ins[r][k] = (row<N)? src[(size_t)row*64+k] : 0.f;
    }
    for (int i=tid;i<4096;i+=256) Ws[i>>6][i&63] = U1[p*4096 + i];
    __syncthreads();
    for (int k=0;k<64;k+=4){
      float4 hv[4];
      #pragma unroll
      for (int j=0;j<4;j++) hv[j] = *(const float4*)&ins[rq*4+j][k];
      #pragma unroll
      for (int kk=0;kk<4;kk++){
        float4 wv = *(const float4*)&Ws[k+kk][dq*4];
        #pragma unroll
        for (int j=0;j<4;j++){
          float v = ((const float*)&hv[j])[kk];
          acc[j][0]+=v*wv.x; acc[j][1]+=v*wv.y; acc[j][2]+=v*wv.z; acc[j][3]+=v*wv.w;
        }
      }
    }
    __syncthreads();
  }
  float ssum[4]={}, ssq[4]={};
  #pragma unroll
  for (int j=0;j<4;j++){
    int row = row0 + rq*4 + j;
    if (row<N){
      *(float4*)(tn+(size_t)row*64+dq*4) = make_float4(acc[j][0],acc[j][1],acc[j][2],acc[j][3]);
      #pragma unroll
      for (int c=0;c<4;c++){ float v=acc[j][c]; ssum[c]+=v; ssq[c]+=v*v; }
    }
  }
  float* red = &ins[0][0];
  #pragma unroll
  for (int c=0;c<4;c++) red[rq*64 + dq*4 + c] = ssum[c];
  __syncthreads();
  if (tid < 64){
    float t=0.f; for (int r=0;r<16;r++) t += red[r*64+tid];
    atomicAdd(&stats3[tid], t);
  }
  __syncthreads();
  #pragma unroll
  for (int c=0;c<4;c++) red[rq*64 + dq*4 + c] = ssq[c];
  __syncthreads();
  if (tid < 64){
    float t=0.f; for (int r=0;r<16;r++) t += red[r*64+tid];
    atomicAdd(&stats3[64+tid], t);
  }
}

// ---- upd layer2: tn = relu(bn3(tn)) @ U2 + b2  (in place) ----
__global__ __launch_bounds__(256) void k_up2(float* __restrict__ tn,
    const float* __restrict__ g3, const float* __restrict__ be3, const float* __restrict__ stats3,
    const float* __restrict__ U2, const float* __restrict__ b2u,
    float* __restrict__ stats4, int N, float invN){
  __shared__ float ys[64][68];
  __shared__ float Ws[64][64];
  __shared__ float scS[64], shS[64], bS[64];
  int tid = threadIdx.x;
  if (tid < 64){
    float m = stats3[tid]*invN;
    float v = stats3[64+tid]*invN - m*m;
    float sc = g3[tid]*rsqrtf(v+EPS);
    scS[tid] = sc; shS[tid] = be3[tid] - m*sc; bS[tid] = b2u[tid];
  }
  for (int i=tid;i<4096;i+=256) Ws[i>>6][i&63] = U2[i];
  int row0 = blockIdx.x*64;
  __syncthreads();
  for (int i=tid;i<4096;i+=256){
    int r=i>>6,k=i&63; int row=row0+r;
    float y = 0.f;
    if (row<N) y = fmaxf(tn[(size_t)row*64+k]*scS[k] + shS[k], 0.f);
    ys[r][k] = y;
  }
  __syncthreads();
  int rq = tid>>4, dq = tid&15;
  float4 b4 = *(const float4*)&bS[dq*4];
  float acc[4][4];
  #pragma unroll
  for (int j=0;j<4;j++){ acc[j][0]=b4.x; acc[j][1]=b4.y; acc[j][2]=b4.z; acc[j][3]=b4.w; }
  for (int k=0;k<64;k+=4){
    float4 hv[4];
    #pragma unroll
    for (int j=0;j<4;j++) hv[j] = *(const float4*)&ys[rq*4+j][k];
    #pragma unroll
    for (int kk=0;kk<4;kk++){
      float4 wv = *(const float4*)&Ws[k+kk][dq*4];
      #pragma unroll
      for (int j=0;j<4;j++){
        float v = ((const float*)&hv[j])[kk];
        acc[j][0]+=v*wv.x; acc[j][1]+=v*wv.y; acc[j][2]+=v*wv.z; acc[j][3]+=v*wv.w;
      }
    }
  }
  float ssum[4]={}, ssq[4]={};
  #pragma unroll
  for (int j=0;j<4;j++){
    int row = row0 + rq*4 + j;
    if (row<N){
      *(float4*)(tn+(size_t)row*64+dq*4) = make_float4(acc[j][0],acc[j][1],acc[j][2],acc[j][3]);
      #pragma unroll
      for (int c=0;c<4;c++){ float v=acc[j][c]; ssum[c]+=v; ssq[c]+=v*v; }
    }
  }
  __syncthreads();
  float* red = &ys[0][0];
  #pragma unroll
  for (int c=0;c<4;c++) red[rq*64 + dq*4 + c] = ssum[c];
  __syncthreads();
  if (tid < 64){
    float t=0.f; for (int r=0;r<16;r++) t += red[r*64+tid];
    atomicAdd(&stats4[tid], t);
  }
  __syncthreads();
  #pragma unroll
  for (int c=0;c<4;c++) red[rq*64 + dq*4 + c] = ssq[c];
  __syncthreads();
  if (tid < 64){
    float t=0.f; for (int r=0;r<16;r++) t += red[r*64+tid];
    atomicAdd(&stats4[64+tid], t);
  }
}

// ---- residual + next-layer P,Q: h += relu(bn4(tn)); P=h@A, Q=h@B ----
__global__ __launch_bounds__(256) void k_res_pq(float* __restrict__ h, const float* __restrict__ tn,
    const float* __restrict__ g4, const float* __restrict__ be4, const float* __restrict__ stats4,
    const float* __restrict__ A, const float* __restrict__ B,
    float* __restrict__ P, float* __restrict__ Q, int N, float invN){
  __shared__ float hs[64][68];
  __shared__ float As[64][64];
  __shared__ float Bs[64][64];
  __shared__ float scS[64], shS[64];
  int tid = threadIdx.x;
  if (tid < 64){
    float m = stats4[tid]*invN;
    float v = stats4[64+tid]*invN - m*m;
    float sc = g4[tid]*rsqrtf(v+EPS);
    scS[tid] = sc; shS[tid] = be4[tid] - m*sc;
  }
  for (int i = tid; i < 4096; i += 256){ As[i>>6][i&63] = A[i]; Bs[i>>6][i&63] = B[i]; }
  int row0 = blockIdx.x*64;
  __syncthreads();
  for (int i = tid; i < 4096; i += 256){
    int r = i>>6, k = i&63; int row = row0+r;
    float hv = 0.f;
    if (row<N){
      hv = h[(size_t)row*64+k] + fmaxf(tn[(size_t)row*64+k]*scS[k] + shS[k], 0.f);
      h[(size_t)row*64+k] = hv;
    }
    hs[r][k] = hv;
  }
  __syncthreads();
  int rq = tid>>4, dq = tid&15;
  float ap[4][4]={}, aq[4][4]={};
  for (int k=0;k<64;k+=4){
    float4 hv[4];
    #pragma unroll
    for (int j=0;j<4;j++) hv[j] = *(const float4*)&hs[rq*4+j][k];
    #pragma unroll
    for (int kk=0;kk<4;kk++){
      float4 av = *(const float4*)&As[k+kk][dq*4];
      float4 bv = *(const float4*)&Bs[k+kk][dq*4];
      #pragma unroll
      for (int j=0;j<4;j++){
        float v = ((const float*)&hv[j])[kk];
        ap[j][0]+=v*av.x; ap[j][1]+=v*av.y; ap[j][2]+=v*av.z; ap[j][3]+=v*av.w;
        aq[j][0]+=v*bv.x; aq[j][1]+=v*bv.y; aq[j][2]+=v*bv.z; aq[j][3]+=v*bv.w;
      }
    }
  }
  #pragma unroll
  for (int j=0;j<4;j++){
    int row = row0 + rq*4 + j;
    if (row<N){
      *(float4*)(P+(size_t)row*64+dq*4) = make_float4(ap[j][0],ap[j][1],ap[j][2],ap[j][3]);
      *(float4*)(Q+(size_t)row*64+dq*4) = make_float4(aq[j][0],aq[j][1],aq[j][2],aq[j][3]);
    }
  }
}

// ---- final: h += relu(bn4(tn)); out = relu(h@Wp+bp) @ Wo + bo ----
__global__ __launch_bounds__(256) void k_res_head(const float* __restrict__ h, const float* __restrict__ tn,
    const float* __restrict__ g4, const float* __restrict__ be4, const float* __restrict__ stats4,
    const float* __restrict__ Wp, const float* __restrict__ bp,
    const float* __restrict__ Wo, const float* __restrict__ bo,
    float* __restrict__ out, int N, float invN){
  __shared__ float hs[64][68];
  __shared__ float Wps[64][64];
  __shared__ float ps[64][68];
  __shared__ float Wos[64][16];
  __shared__ float scS[64], shS[64];
  int tid = threadIdx.x;
  if (tid < 64){
    float m = stats4[tid]*invN;
    float v = stats4[64+tid]*invN - m*m;
    float sc = g4[tid]*rsqrtf(v+EPS);
    scS[tid] = sc; shS[tid] = be4[tid] - m*sc;
  }
  for (int i=tid;i<4096;i+=256) Wps[i>>6][i&63] = Wp[i];
  for (int i=tid;i<1024;i+=256) Wos[i>>4][i&15] = Wo[i];
  int row0 = blockIdx.x*64;
  __syncthreads();
  for (int i = tid; i < 4096; i += 256){
    int r = i>>6, k = i&63; int row = row0+r;
    float hv = 0.f;
    if (row<N)
      hv = h[(size_t)row*64+k] + fmaxf(tn[(size_t)row*64+k]*scS[k] + shS[k], 0.f);
    hs[r][k] = hv;
  }
  __syncthreads();
  int rq = tid>>4, dq = tid&15;
  float4 b4 = *(const float4*)(bp + dq*4);
  float acc[4][4];
  #pragma unroll
  for (int j=0;j<4;j++){ acc[j][0]=b4.x; acc[j][1]=b4.y; acc[j][2]=b4.z; acc[j][3]=b4.w; }
  for (int k=0;k<64;k+=4){
    float4 hv[4];
    #pragma unroll
    for (int j=0;j<4;j++) hv[j] = *(const float4*)&hs[rq*4+j][k];
    #pragma unroll
    for (int kk=0;kk<4;kk++){
      float4 wv = *(const float4*)&Wps[k+kk][dq*4];
      #pragma unroll
      for (int j=0;j<4;j++){
        float v = ((const float*)&hv[j])[kk];
        acc[j][0]+=v*wv.x; acc[j][1]+=v*wv.y; acc[j][2]+=v*wv.z; acc[j][3]+=v*wv.w;
      }
    }
  }
  #pragma unroll
  for (int j=0;j<4;j++){
    *(float4*)&ps[rq*4+j][dq*4] = make_float4(fmaxf(acc[j][0],0.f), fmaxf(acc[j][1],0.f),
                                              fmaxf(acc[j][2],0.f), fmaxf(acc[j][3],0.f));
  }
  __syncthreads();
  int f = tid & 15;
  float bof = bo[f];
  float acc2[4] = {bof, bof, bof, bof};
  for (int k=0;k<64;k++){
    float wv = Wos[k][f];
    #pragma unroll
    for (int j=0;j<4;j++) acc2[j] += ps[rq*4+j][k]*wv;
  }
  #pragma unroll
  for (int j=0;j<4;j++){
    int row = row0 + rq*4 + j;
    if (row<N) out[(size_t)row*16 + f] = acc2[j];
  }
}

extern "C" void kernel_launch(void* const* d_in, const int* in_sizes, int n_in,
                              void* d_out, int out_size, void* d_ws, size_t ws_size,
                              hipStream_t stream){
  const float* x    = (const float*)d_in[0];
  const float* eatt = (const float*)d_in[1];
  const float* Win  = (const float*)d_in[2];
  const float* bin  = (const float*)d_in[3];
  const float* mW1  = (const float*)d_in[4];
  const float* mb1  = (const float*)d_in[5];
  const float* mg1  = (const float*)d_in[6];
  const float* mbe1 = (const float*)d_in[7];
  const float* mW2  = (const float*)d_in[8];
  const float* mb2  = (const float*)d_in[9];
  const float* mg2  = (const float*)d_in[10];
  const float* mbe2 = (const float*)d_in[11];
  const float* uW1  = (const float*)d_in[12];
  const float* ub1  = (const float*)d_in[13];
  const float* ug1  = (const float*)d_in[14];
  const float* ube1 = (const float*)d_in[15];
  const float* uW2  = (const float*)d_in[16];
  const float* ub2  = (const float*)d_in[17];
  const float* ug2  = (const float*)d_in[18];
  const float* ube2 = (const float*)d_in[19];
  const float* predW = (const float*)d_in[24];
  const float* predb = (const float*)d_in[25];
  const float* poutW = (const float*)d_in[26];
  const float* poutb = (const float*)d_in[27];
  const int*   ei    = (const int*)d_in[28];

  const int N = in_sizes[0] / 18;
  const int E = in_sizes[1];

  size_t nodeB = (size_t)N * 64 * sizeof(float);
  size_t t2B   = (size_t)E * 64 * sizeof(u16);
  size_t statsB = 16 * 128 * sizeof(float);

  bool planA = ws_size >= 3*nodeB + t2B + statsB;

  char* w = (char*)d_ws;
  float* h = (float*)w; w += nodeB;
  float* P = (float*)w; w += nodeB;
  float* Q = (float*)w; w += nodeB;
  u16*  t2 = nullptr;
  float* agg;
  float* tn;
  float* stats;
  if (planA){
    t2 = (u16*)w; w += t2B;
    stats = (float*)w;
    agg = P;   // P dead after k_m2s (its data already baked into t2)
    tn  = Q;   // Q dead after k_t1; k_res_pq reads tn=Q block-locally before writing Q
  } else {
    agg = (float*)w; w += nodeB;
    stats = (float*)w;
    tn = P;
  }

  hipMemsetAsync(stats, 0, statsB, stream);

  int nb = (N + 63)/64;
  float invE = 1.0f/(float)E, invN = 1.0f/(float)N;

  k_in<<<nb, 256, 0, stream>>>(x, Win, bin, h, N);
  k_pq<<<nb, 256, 0, stream>>>(h, mW1, mW1 + 4096, P, Q, N);

  for (int l = 0; l < 4; ++l){
    float* s1 = stats + (l*4+0)*128;
    float* s2 = stats + (l*4+1)*128;
    float* s3 = stats + (l*4+2)*128;
    float* s4 = stats + (l*4+3)*128;
    const float* A  = mW1 + (size_t)l*8256;
    const float* c1 = A + 8192;
    if (planA){
      k_t1<<<2048, 256, 0, stream>>>(P, Q, eatt, ei, c1, mb1 + l*64, t2, s1, E);
      k_m2s<<<1024, 256, 0, stream>>>(t2, mg1 + l*64, mbe1 + l*64, s1,
                                      mW2 + (size_t)l*4096, mb2 + l*64, s2, E, invE);
      hipMemsetAsync(agg, 0, nodeB, stream);
      k_sc<<<2048, 256, 0, stream>>>(t2, ei, mg2 + l*64, mbe2 + l*64, s2, agg, E, invE);
    } else {
      k_s1<<<2048, 256, 0, stream>>>(P, Q, eatt, ei, c1, mb1 + l*64, s1, E);
      k_m2b<<<1024, 256, 0, stream>>>(P, Q, eatt, ei, c1, mb1 + l*64, mg1 + l*64, mbe1 + l*64,
                                      s1, mW2 + (size_t)l*4096, mb2 + l*64, s2, E, invE);
      hipMemsetAsync(agg, 0, nodeB, stream);
      k_sc_rec<<<1024, 256, 0, stream>>>(P, Q, eatt, ei, c1, mb1 + l*64, mg1 + l*64, mbe1 + l*64,
                                         s1, mW2 + (size_t)l*4096, mb2 + l*64,
                                         mg2 + l*64, mbe2 + l*64, s2, agg, E, invE);
    }
    k_up1<<<nb, 256, 0, stream>>>(h, agg, uW1 + (size_t)l*8192, ub1 + l*64, tn, s3, N);
    k_up2<<<nb, 256, 0, stream>>>(tn, ug1 + l*64, ube1 + l*64, s3, uW2 + (size_t)l*4096,
                                  ub2 + l*64, s4, N, invN);
    if (l < 3){
      const float* An = mW1 + (size_t)(l+1)*8256;
      k_res_pq<<<nb, 256, 0, stream>>>(h, tn, ug2 + l*64, ube2 + l*64, s4,
                                       An, An + 4096, P, Q, N, invN);
    } else {
      k_res_head<<<nb, 256, 0, stream>>>(h, tn, ug2 + l*64, ube2 + l*64, s4,
                                         predW, predb, poutW, poutb, (float*)d_out, N, invN);
    }
  }
}